// Round 1
// baseline (240.478 us; speedup 1.0000x reference)
//
#include <hip/hip_runtime.h>
#include <hip/hip_bf16.h>

// Problem constants
#define B_    256
#define CIN   64
#define COUT  64
#define H_    1855
#define K_    6
#define KDIM  448          // (1 center + 6 neighbors) * 64 channels
#define NSTEP 14           // 448 / 32 (K per MFMA)
#define HT    64           // h-tile per block
#define NHT   29           // ceil(1855/64)

typedef __bf16 bf16x8 __attribute__((ext_vector_type(8)));
typedef float  f32x4  __attribute__((ext_vector_type(4)));

static __device__ inline unsigned short f2bf(float f) {
    __hip_bfloat16 h = __float2bfloat16(f);
    return *reinterpret_cast<unsigned short*>(&h);
}

// ---------------------------------------------------------------------------
// Kernel 1: pack weights into MFMA A-fragment order (bf16) + compute 1/total_valid
// W2 element e = ((s*4 + t)*64 + l)*8 + j  maps to  o = t*16 + (l&15),
// k = s*32 + (l>>4)*8 + j   (k = slot*64 + c ; slot 0 = center, 1..6 = neighbors)
// ---------------------------------------------------------------------------
__global__ void prep_weights(const float* __restrict__ wc,
                             const float* __restrict__ wn,
                             const int*   __restrict__ nb,
                             unsigned short* __restrict__ W2,
                             float* __restrict__ inv_tv) {
    int e = blockIdx.x * 256 + threadIdx.x;     // 0 .. 28671
    int j = e & 7;
    int l = (e >> 3) & 63;
    int t = (e >> 9) & 3;
    int s = e >> 11;
    int o = t * 16 + (l & 15);
    int k = s * 32 + (l >> 4) * 8 + j;
    int slot = k >> 6;
    int c = k & 63;
    float v = (slot == 0) ? wc[o * 64 + c]
                          : wn[(o * 64 + c) * 6 + (slot - 1)];
    W2[e] = f2bf(v);
    if (e == 0) {
        int cnt = 1;
        #pragma unroll
        for (int q = 0; q < 6; ++q) cnt += (nb[q] >= 0) ? 1 : 0;
        *inv_tv = 1.0f / (float)cnt;
    }
}

// ---------------------------------------------------------------------------
// Kernel 2: transpose + convert  x (B, C, H) fp32  ->  xT (B, H, C) bf16
// so a feature vector (b,h,:) is 128 contiguous bytes (gather-friendly).
// ---------------------------------------------------------------------------
__global__ void transpose_bf16(const float* __restrict__ x,
                               unsigned short* __restrict__ xT) {
    __shared__ __align__(16) unsigned short tile[64][72];  // +8 pad
    int b  = blockIdx.y;
    int h0 = blockIdx.x * HT;
    int t  = threadIdx.x;
    int ho = t & 63;
    int cq = t >> 6;                       // 0..3
    const float* xb = x + (size_t)b * CIN * H_;
    int h = h0 + ho;
    #pragma unroll
    for (int i = 0; i < 16; ++i) {
        int c = i * 4 + cq;
        float v = (h < H_) ? xb[(size_t)c * H_ + h] : 0.f;
        tile[ho][c] = f2bf(v);
    }
    __syncthreads();
    #pragma unroll
    for (int rep = 0; rep < 2; ++rep) {
        int task = rep * 256 + t;          // 0..511  = 64 rows * 8 chunks
        int hh = task >> 3;
        int j  = task & 7;
        int hw = h0 + hh;
        if (hw < H_) {
            *reinterpret_cast<uint4*>(&xT[((size_t)b * H_ + hw) * 64 + j * 8]) =
                *reinterpret_cast<const uint4*>(&tile[hh][j * 8]);
        }
    }
}

// ---------------------------------------------------------------------------
// Kernel 3: gather + MFMA GEMM.
// Block = (h-tile of 64, b). 256 threads = 4 waves; wave w computes
// out[b, 0:64, h0 + w*16 : +16]  (4 o-tiles of 16x16, K = 448 in 14 steps).
// ---------------------------------------------------------------------------
__global__ __launch_bounds__(256, 2) void conv_main(
        const unsigned short* __restrict__ xT,
        const unsigned short* __restrict__ W2,
        const int*   __restrict__ nb,
        const float* __restrict__ bias,
        const float* __restrict__ inv_tv,
        float* __restrict__ out) {
    // feat[h_local][k], k-contiguous; row = 448 + 8 pad bf16 = 912 B (16B-aligned)
    __shared__ __align__(16) unsigned short feat[HT][KDIM + 8];

    int b  = blockIdx.y;
    int h0 = blockIdx.x * HT;
    int t  = threadIdx.x;

    // ---- stage gathered features into LDS -------------------------------
    for (int slot = 0; slot < 7; ++slot) {
        #pragma unroll
        for (int rep = 0; rep < 2; ++rep) {
            int task = rep * 256 + t;       // 512 tasks = 64 h * 8 chunks
            int hl = task >> 3;
            int j  = task & 7;
            int h  = h0 + hl;
            int n  = -1;
            if (h < H_) n = (slot == 0) ? h : nb[h * 6 + (slot - 1)];
            uint4 v = make_uint4(0u, 0u, 0u, 0u);
            if (n >= 0)
                v = *reinterpret_cast<const uint4*>(
                        &xT[((size_t)b * H_ + n) * 64 + j * 8]);
            *reinterpret_cast<uint4*>(&feat[hl][slot * 64 + j * 8]) = v;
        }
    }
    __syncthreads();

    // ---- MFMA K-loop ----------------------------------------------------
    int w  = t >> 6;          // wave id: h sub-tile
    int l  = t & 63;
    int lr = l & 15;          // col within tile (h) / row of A
    int lg = l >> 4;          // k-group / D row group

    f32x4 acc[4];
    #pragma unroll
    for (int i = 0; i < 4; ++i) acc[i] = (f32x4){0.f, 0.f, 0.f, 0.f};

    const bf16x8* __restrict__ Wf = reinterpret_cast<const bf16x8*>(W2);

    #pragma unroll
    for (int s = 0; s < NSTEP; ++s) {
        bf16x8 bfrag = *reinterpret_cast<const bf16x8*>(
                &feat[w * 16 + lr][s * 32 + lg * 8]);
        #pragma unroll
        for (int tt = 0; tt < 4; ++tt) {
            bf16x8 afrag = Wf[(s * 4 + tt) * 64 + l];
            acc[tt] = __builtin_amdgcn_mfma_f32_16x16x32_bf16(
                          afrag, bfrag, acc[tt], 0, 0, 0);
        }
    }

    // ---- epilogue: scale + bias, predicated store -----------------------
    float inv = *inv_tv;
    int h = h0 + w * 16 + lr;
    if (h < H_) {
        float* ob = out + (size_t)b * COUT * H_ + h;
        #pragma unroll
        for (int tt = 0; tt < 4; ++tt) {
            #pragma unroll
            for (int r = 0; r < 4; ++r) {
                int o = tt * 16 + lg * 4 + r;
                ob[(size_t)o * H_] = acc[tt][r] * inv + bias[o];
            }
        }
    }
}

// ---------------------------------------------------------------------------
extern "C" void kernel_launch(void* const* d_in, const int* in_sizes, int n_in,
                              void* d_out, int out_size, void* d_ws, size_t ws_size,
                              hipStream_t stream) {
    const float* x    = (const float*)d_in[0];
    const int*   nb   = (const int*)  d_in[1];
    const float* wc   = (const float*)d_in[2];
    const float* wn   = (const float*)d_in[3];
    const float* bias = (const float*)d_in[4];
    float* out = (float*)d_out;

    char* ws = (char*)d_ws;
    unsigned short* W2     = (unsigned short*)ws;            // 57,344 B
    float*          inv_tv = (float*)(ws + 57344);           // 4 B
    unsigned short* xT     = (unsigned short*)(ws + 57600);  // 60,784,640 B

    prep_weights<<<112, 256, 0, stream>>>(wc, wn, nb, W2, inv_tv);

    dim3 grid(NHT, B_);
    transpose_bf16<<<grid, 256, 0, stream>>>(x, xT);
    conv_main<<<grid, 256, 0, stream>>>(xT, W2, nb, bias, inv_tv, out);
}

// Round 2
// 145.743 us; speedup vs baseline: 1.6500x; 1.6500x over previous
//
#include <hip/hip_runtime.h>
#include <hip/hip_bf16.h>

// Problem constants
#define B_    256
#define CIN   64
#define COUT  64
#define H_    1855
#define K_    6
#define KDIM  448          // (1 center + 6 neighbors) * 64 channels
#define NSTEP 14           // 448 / 32 (K per MFMA)
#define HT    64           // h-tile per block
#define NHT   29           // ceil(1855/64)
#define NWG   (NHT * B_)   // 7424 blocks, % 8 == 0
#define CPX   (NWG / 8)    // 928 blocks per XCD chunk

typedef __bf16 bf16x8 __attribute__((ext_vector_type(8)));
typedef float  f32x4  __attribute__((ext_vector_type(4)));

typedef __attribute__((address_space(3))) unsigned int       lds_u32;
typedef const __attribute__((address_space(1))) unsigned int glb_u32;

static __device__ inline unsigned short f2bf(float f) {
    __hip_bfloat16 h = __float2bfloat16(f);
    return *reinterpret_cast<unsigned short*>(&h);
}

// ---------------------------------------------------------------------------
// Kernel 1: pack weights into MFMA A-fragment order (bf16) + compute 1/total_valid
// W2 element e = ((s*4 + t)*64 + l)*8 + j  maps to  o = t*16 + (l&15),
// k = s*32 + (l>>4)*8 + j   (k = slot*64 + c ; slot 0 = center, 1..6 = neighbors)
// ---------------------------------------------------------------------------
__global__ void prep_weights(const float* __restrict__ wc,
                             const float* __restrict__ wn,
                             const int*   __restrict__ nb,
                             unsigned short* __restrict__ W2,
                             float* __restrict__ inv_tv) {
    int e = blockIdx.x * 256 + threadIdx.x;     // 0 .. 28671
    int j = e & 7;
    int l = (e >> 3) & 63;
    int t = (e >> 9) & 3;
    int s = e >> 11;
    int o = t * 16 + (l & 15);
    int k = s * 32 + (l >> 4) * 8 + j;
    int slot = k >> 6;
    int c = k & 63;
    float v = (slot == 0) ? wc[o * 64 + c]
                          : wn[(o * 64 + c) * 6 + (slot - 1)];
    W2[e] = f2bf(v);
    if (e == 0) {
        int cnt = 1;
        #pragma unroll
        for (int q = 0; q < 6; ++q) cnt += (nb[q] >= 0) ? 1 : 0;
        *inv_tv = 1.0f / (float)cnt;
    }
}

// ---------------------------------------------------------------------------
// Kernel 2: transpose + convert  x (B, C, H) fp32  ->  xT (B, H, C) bf16
// so a feature vector (b,h,:) is 128 contiguous bytes (gather-friendly).
// ---------------------------------------------------------------------------
__global__ void transpose_bf16(const float* __restrict__ x,
                               unsigned short* __restrict__ xT) {
    __shared__ __align__(16) unsigned short tile[64][72];  // +8 pad
    int b  = blockIdx.y;
    int h0 = blockIdx.x * HT;
    int t  = threadIdx.x;
    int ho = t & 63;
    int cq = t >> 6;                       // 0..3
    const float* xb = x + (size_t)b * CIN * H_;
    int h = h0 + ho;
    #pragma unroll
    for (int i = 0; i < 16; ++i) {
        int c = i * 4 + cq;
        float v = (h < H_) ? xb[(size_t)c * H_ + h] : 0.f;
        tile[ho][c] = f2bf(v);
    }
    __syncthreads();
    #pragma unroll
    for (int rep = 0; rep < 2; ++rep) {
        int task = rep * 256 + t;          // 0..511  = 64 rows * 8 chunks
        int hh = task >> 3;
        int j  = task & 7;
        int hw = h0 + hh;
        if (hw < H_) {
            *reinterpret_cast<uint4*>(&xT[((size_t)b * H_ + hw) * 64 + j * 8]) =
                *reinterpret_cast<const uint4*>(&tile[hh][j * 8]);
        }
    }
}

// ---------------------------------------------------------------------------
// Kernel 3: gather (global_load_lds, swizzled) + MFMA GEMM, W in VGPRs.
// 512 threads = 8 waves = 2 o-groups x 4 h-subtiles. Per wave: 2 o-tiles of
// 16x16 over its 16-h subtile, K=448 in 14 MFMA steps, A-fragments in regs.
// feat LDS layout: [slot][h][128B row], 16B units XOR-swizzled by (h&7).
// ---------------------------------------------------------------------------
__global__ __launch_bounds__(512, 4) void conv_main(
        const unsigned short* __restrict__ xT,
        const unsigned short* __restrict__ W2,
        const int*   __restrict__ nb,
        const float* __restrict__ bias,
        const float* __restrict__ inv_tv,
        const unsigned short* __restrict__ zbuf,
        float* __restrict__ out) {
    __shared__ __align__(16) unsigned short feat[7 * 64 * 64]; // 57,344 B

    int bid = blockIdx.x;
    int swz = (bid & 7) * CPX + (bid >> 3);   // bijective: NWG % 8 == 0
    int b   = swz / NHT;
    int h0  = (swz % NHT) * HT;

    int t = threadIdx.x;
    int w = t >> 6;          // wave 0..7
    int l = t & 63;

    // ---- staging: thread t handles (hl = t>>3, 16B chunk j = t&7) --------
    int hl   = t >> 3;                 // 0..63
    int j    = t & 7;
    int h    = h0 + hl;
    int jsrc = j ^ (hl & 7);           // source-side inverse of read swizzle

    int nidx[7];
    nidx[0] = (h < H_) ? h : -1;
    #pragma unroll
    for (int q = 0; q < 6; ++q)
        nidx[q + 1] = (h < H_) ? nb[h * 6 + q] : -1;

    const unsigned short* xbase = xT + (size_t)b * H_ * 64;

    #pragma unroll
    for (int slot = 0; slot < 7; ++slot) {
        int n = nidx[slot];
        const unsigned short* src = (n >= 0)
            ? (xbase + (size_t)n * 64 + jsrc * 8)
            : (zbuf + jsrc * 8);
        // wave-uniform LDS base; lane l lands at base + l*16 (linear dest)
        unsigned short* dst = &feat[slot * 4096 + w * 512];
        __builtin_amdgcn_global_load_lds((glb_u32*)src, (lds_u32*)dst, 16, 0, 0);
    }

    // ---- hoist W fragments into registers (overlaps with staging) -------
    int og = w & 1;          // o-group: o in [og*32, og*32+32)
    int hh = w >> 1;         // h-subtile: h in [h0 + hh*16, +16)
    const bf16x8* __restrict__ Wf = reinterpret_cast<const bf16x8*>(W2);
    bf16x8 wr[NSTEP][2];
    #pragma unroll
    for (int s = 0; s < NSTEP; ++s)
        #pragma unroll
        for (int u = 0; u < 2; ++u)
            wr[s][u] = Wf[(s * 4 + og * 2 + u) * 64 + l];

    __syncthreads();  // drains vmcnt(0): staging + W loads complete

    // ---- MFMA K-loop: pure LDS reads + MFMA ------------------------------
    int lr = l & 15;
    int lg = l >> 4;
    int hrow = hh * 16 + lr;           // 0..63
    f32x4 acc[2];
    acc[0] = (f32x4){0.f, 0.f, 0.f, 0.f};
    acc[1] = (f32x4){0.f, 0.f, 0.f, 0.f};

    #pragma unroll
    for (int s = 0; s < NSTEP; ++s) {
        int c16 = (((s & 1) * 4 + lg)) ^ (hrow & 7);   // read-side swizzle
        bf16x8 bfrag = *reinterpret_cast<const bf16x8*>(
                &feat[(s >> 1) * 4096 + hrow * 64 + c16 * 8]);
        acc[0] = __builtin_amdgcn_mfma_f32_16x16x32_bf16(wr[s][0], bfrag, acc[0], 0, 0, 0);
        acc[1] = __builtin_amdgcn_mfma_f32_16x16x32_bf16(wr[s][1], bfrag, acc[1], 0, 0, 0);
    }

    // ---- epilogue --------------------------------------------------------
    float inv = *inv_tv;
    int hout = h0 + hrow;
    if (hout < H_) {
        float* ob = out + (size_t)b * COUT * H_ + hout;
        #pragma unroll
        for (int u = 0; u < 2; ++u) {
            #pragma unroll
            for (int r = 0; r < 4; ++r) {
                int o = og * 32 + u * 16 + lg * 4 + r;
                ob[(size_t)o * H_] = acc[u][r] * inv + bias[o];
            }
        }
    }
}

// ---------------------------------------------------------------------------
extern "C" void kernel_launch(void* const* d_in, const int* in_sizes, int n_in,
                              void* d_out, int out_size, void* d_ws, size_t ws_size,
                              hipStream_t stream) {
    const float* x    = (const float*)d_in[0];
    const int*   nb   = (const int*)  d_in[1];
    const float* wc   = (const float*)d_in[2];
    const float* wn   = (const float*)d_in[3];
    const float* bias = (const float*)d_in[4];
    float* out = (float*)d_out;

    char* ws = (char*)d_ws;
    unsigned short* W2     = (unsigned short*)ws;            // 57,344 B
    float*          inv_tv = (float*)(ws + 57344);           // 4 B
    unsigned short* zbuf   = (unsigned short*)(ws + 57472);  // 128 B zero
    unsigned short* xT     = (unsigned short*)(ws + 57600);  // 60,784,640 B

    hipMemsetAsync(zbuf, 0, 128, stream);
    prep_weights<<<112, 256, 0, stream>>>(wc, wn, nb, W2, inv_tv);

    dim3 tgrid(NHT, B_);
    transpose_bf16<<<tgrid, 256, 0, stream>>>(x, xT);
    conv_main<<<NWG, 512, 0, stream>>>(xT, W2, nb, bias, inv_tv, zbuf, out);
}

// Round 3
// 118.004 us; speedup vs baseline: 2.0379x; 1.2351x over previous
//
#include <hip/hip_runtime.h>
#include <hip/hip_bf16.h>

// Problem constants
#define B_    256
#define CIN   64
#define COUT  64
#define H_    1855
#define K_    6
#define KDIM  448          // (1 center + 6 neighbors) * 64 channels
#define NSTEP 14           // 448 / 32 (K per MFMA)
#define HT    64           // h-tile for transpose kernel
#define NHT   29           // ceil(1855/64)

// conv_main tiling
#define HT2   32           // h rows per conv tile
#define TPB   58           // tiles per b = ceil(1855/32)
#define NTILE (TPB * B_)   // 14848
#define TPBLK 8            // tiles per block
#define NBLK  (NTILE / TPBLK)   // 1856, % 8 == 0
#define CPX2  (NBLK / 8)        // 232

typedef __bf16 bf16x8 __attribute__((ext_vector_type(8)));
typedef float  f32x4  __attribute__((ext_vector_type(4)));

typedef __attribute__((address_space(3))) unsigned int       lds_u32;
typedef const __attribute__((address_space(1))) unsigned int glb_u32;

static __device__ inline unsigned short f2bf(float f) {
    __hip_bfloat16 h = __float2bfloat16(f);
    return *reinterpret_cast<unsigned short*>(&h);
}

// ---------------------------------------------------------------------------
// Kernel 1: pack weights into MFMA A-fragment order (bf16) + 1/total_valid
// ---------------------------------------------------------------------------
__global__ void prep_weights(const float* __restrict__ wc,
                             const float* __restrict__ wn,
                             const int*   __restrict__ nb,
                             unsigned short* __restrict__ W2,
                             float* __restrict__ inv_tv) {
    int e = blockIdx.x * 256 + threadIdx.x;     // 0 .. 28671
    int j = e & 7;
    int l = (e >> 3) & 63;
    int t = (e >> 9) & 3;
    int s = e >> 11;
    int o = t * 16 + (l & 15);
    int k = s * 32 + (l >> 4) * 8 + j;
    int slot = k >> 6;
    int c = k & 63;
    float v = (slot == 0) ? wc[o * 64 + c]
                          : wn[(o * 64 + c) * 6 + (slot - 1)];
    W2[e] = f2bf(v);
    if (e == 0) {
        int cnt = 1;
        #pragma unroll
        for (int q = 0; q < 6; ++q) cnt += (nb[q] >= 0) ? 1 : 0;
        *inv_tv = 1.0f / (float)cnt;
    }
}

// ---------------------------------------------------------------------------
// Kernel 2: transpose + convert  x (B, C, H) fp32  ->  xT (B, H, C) bf16
// ---------------------------------------------------------------------------
__global__ void transpose_bf16(const float* __restrict__ x,
                               unsigned short* __restrict__ xT) {
    __shared__ __align__(16) unsigned short tile[64][72];  // +8 pad
    int b  = blockIdx.y;
    int h0 = blockIdx.x * HT;
    int t  = threadIdx.x;
    int ho = t & 63;
    int cq = t >> 6;                       // 0..3
    const float* xb = x + (size_t)b * CIN * H_;
    int h = h0 + ho;
    #pragma unroll
    for (int i = 0; i < 16; ++i) {
        int c = i * 4 + cq;
        float v = (h < H_) ? xb[(size_t)c * H_ + h] : 0.f;
        tile[ho][c] = f2bf(v);
    }
    __syncthreads();
    #pragma unroll
    for (int rep = 0; rep < 2; ++rep) {
        int task = rep * 256 + t;          // 0..511  = 64 rows * 8 chunks
        int hh = task >> 3;
        int j  = task & 7;
        int hw = h0 + hh;
        if (hw < H_) {
            *reinterpret_cast<uint4*>(&xT[((size_t)b * H_ + hw) * 64 + j * 8]) =
                *reinterpret_cast<const uint4*>(&tile[hh][j * 8]);
        }
    }
}

// ---------------------------------------------------------------------------
// Kernel 3: persistent 8-tile pipeline. 512 threads = 8 waves.
// Staging: wave w (w<7) owns slot w of the NEXT tile via 4 global_load_lds
// (16B, XOR-swizzled source). Counted vmcnt keeps staging in flight across
// the barrier; compute of tile i overlaps staging of tile i+1.
// Compute: wave w -> o-tile og=w&3, h-subtile hh=w>>2; 14 MFMA per tile.
// ---------------------------------------------------------------------------
__global__ __launch_bounds__(512, 4) void conv_main(
        const unsigned short* __restrict__ xT,
        const unsigned short* __restrict__ W2,
        const int*   __restrict__ nb,
        const float* __restrict__ bias,
        const float* __restrict__ inv_tv,
        const unsigned short* __restrict__ zbuf,
        float* __restrict__ out) {
    __shared__ __align__(16) unsigned short feat[2][7][HT2][64]; // 57,344 B

    int bid = blockIdx.x;
    int swz   = (bid & 7) * CPX2 + (bid >> 3);   // bijective XCD swizzle
    int gbase = swz * TPBLK;

    int t = threadIdx.x;
    int w = t >> 6;          // wave 0..7
    int l = t & 63;

    // staging lane constants
    int lrow = l >> 3;                  // h row within an 8-row chunk
    int jsrc = (l & 7) ^ lrow;          // source 16B unit (inverse of read swz)
    int q    = w - 1;                   // neighbor index for waves 1..6

    // compute lane constants
    int og = w & 3, hh = w >> 2;
    int lr = l & 15, lg = l >> 4;
    int hrow = hh * 16 + lr;            // 0..31

    // hoist W fragments + epilogue constants
    const bf16x8* __restrict__ Wf = reinterpret_cast<const bf16x8*>(W2);
    bf16x8 wr[NSTEP];
    #pragma unroll
    for (int s = 0; s < NSTEP; ++s) wr[s] = Wf[(s * 4 + og) * 64 + l];
    float inv = *inv_tv;
    float bv[4];
    #pragma unroll
    for (int r = 0; r < 4; ++r) bv[r] = bias[og * 16 + lg * 4 + r];

    int nbv[4];       // neighbor rows for the tile being staged next
    int bn, h0n;      // b / h0 of that tile

    // ---- prologue: stage tile 0, prefetch nbv for tile 1 -----------------
    if (w < 7) {
        int b0  = gbase / TPB;
        int h00 = (gbase - b0 * TPB) * HT2;
        #pragma unroll
        for (int c = 0; c < 4; ++c) {
            int h = h00 + c * 8 + lrow;
            nbv[c] = (h < H_) ? ((w == 0) ? h : nb[h * 6 + q]) : -1;
        }
        const unsigned short* xb = xT + (size_t)b0 * H_ * 64;
        #pragma unroll
        for (int c = 0; c < 4; ++c) {
            int n = nbv[c];
            const unsigned short* src = (n >= 0)
                ? (xb + (size_t)n * 64 + jsrc * 8) : (zbuf + jsrc * 8);
            __builtin_amdgcn_global_load_lds((glb_u32*)src,
                (lds_u32*)&feat[0][w][c * 8][0], 16, 0, 0);
        }
        int g1 = gbase + 1;
        bn  = g1 / TPB;
        h0n = (g1 - bn * TPB) * HT2;
        #pragma unroll
        for (int c = 0; c < 4; ++c) {
            int h = h0n + c * 8 + lrow;
            nbv[c] = (h < H_) ? ((w == 0) ? h : nb[h * 6 + q]) : -1;
        }
    }

    // ---- main loop over 8 tiles -----------------------------------------
    #pragma unroll 2
    for (int i = 0; i < TPBLK; ++i) {
        // A: issue staging for tile i+1 into buf[(i+1)&1]
        if (i < TPBLK - 1 && w < 7) {
            const unsigned short* xb = xT + (size_t)bn * H_ * 64;
            #pragma unroll
            for (int c = 0; c < 4; ++c) {
                int n = nbv[c];
                const unsigned short* src = (n >= 0)
                    ? (xb + (size_t)n * 64 + jsrc * 8) : (zbuf + jsrc * 8);
                __builtin_amdgcn_global_load_lds((glb_u32*)src,
                    (lds_u32*)&feat[(i + 1) & 1][w][c * 8][0], 16, 0, 0);
            }
        }
        // B: prefetch nbv for tile i+2
        if (i < TPBLK - 2 && w < 7) {
            int g2 = gbase + i + 2;
            bn  = g2 / TPB;
            h0n = (g2 - bn * TPB) * HT2;
            #pragma unroll
            for (int c = 0; c < 4; ++c) {
                int h = h0n + c * 8 + lrow;
                nbv[c] = (h < H_) ? ((w == 0) ? h : nb[h * 6 + q]) : -1;
            }
        }
        // C: counted wait — tile i's staging (issued last iter) is complete.
        // Ops newer than it: 4 g_lds + 4 nb for loader waves (8); wave 0 has
        // no nb loads (4); last iteration has no new staging (4).
        if (w == 0 || i == TPBLK - 1)
            asm volatile("s_waitcnt vmcnt(4)" ::: "memory");
        else
            asm volatile("s_waitcnt vmcnt(8)" ::: "memory");
        __builtin_amdgcn_s_barrier();
        __builtin_amdgcn_sched_barrier(0);

        // E: compute tile i from buf[i&1]
        int cb = i & 1;
        f32x4 acc = (f32x4){0.f, 0.f, 0.f, 0.f};
        #pragma unroll
        for (int s = 0; s < NSTEP; ++s) {
            int c16 = (((s & 1) * 4 + lg)) ^ (hrow & 7);
            bf16x8 bfrag = *reinterpret_cast<const bf16x8*>(
                    &feat[cb][s >> 1][hrow][c16 * 8]);
            acc = __builtin_amdgcn_mfma_f32_16x16x32_bf16(wr[s], bfrag, acc, 0, 0, 0);
        }

        // F: epilogue for tile i
        int g    = gbase + i;
        int curb = g / TPB;
        int curh = (g - curb * TPB) * HT2 + hrow;
        if (curh < H_) {
            float* ob = out + (size_t)curb * COUT * H_ + curh;
            #pragma unroll
            for (int r = 0; r < 4; ++r)
                ob[(size_t)(og * 16 + lg * 4 + r) * H_] = acc[r] * inv + bv[r];
        }

        // G: all reads of buf[i&1] done before next iter overwrites it
        __builtin_amdgcn_s_barrier();
    }
}

// ---------------------------------------------------------------------------
extern "C" void kernel_launch(void* const* d_in, const int* in_sizes, int n_in,
                              void* d_out, int out_size, void* d_ws, size_t ws_size,
                              hipStream_t stream) {
    const float* x    = (const float*)d_in[0];
    const int*   nb   = (const int*)  d_in[1];
    const float* wc   = (const float*)d_in[2];
    const float* wn   = (const float*)d_in[3];
    const float* bias = (const float*)d_in[4];
    float* out = (float*)d_out;

    char* ws = (char*)d_ws;
    unsigned short* W2     = (unsigned short*)ws;            // 57,344 B
    float*          inv_tv = (float*)(ws + 57344);           // 4 B
    unsigned short* zbuf   = (unsigned short*)(ws + 57472);  // 128 B zero
    unsigned short* xT     = (unsigned short*)(ws + 57600);  // 60,784,640 B

    hipMemsetAsync(zbuf, 0, 128, stream);
    prep_weights<<<112, 256, 0, stream>>>(wc, wn, nb, W2, inv_tv);

    dim3 tgrid(NHT, B_);
    transpose_bf16<<<tgrid, 256, 0, stream>>>(x, xT);
    conv_main<<<NBLK, 512, 0, stream>>>(xT, W2, nb, bias, inv_tv, zbuf, out);
}

// Round 4
// 115.597 us; speedup vs baseline: 2.0803x; 1.0208x over previous
//
#include <hip/hip_runtime.h>
#include <hip/hip_bf16.h>

// Problem constants
#define B_    256
#define CIN   64
#define COUT  64
#define H_    1855
#define K_    6
#define KDIM  448          // (1 center + 6 neighbors) * 64 channels
#define NSTEP 14           // 448 / 32 (K per MFMA)
#define HT    64           // h-tile for transpose kernel
#define NHT   29           // ceil(1855/64)

// conv_main tiling
#define HT2   32           // h rows per conv tile
#define TPB   58           // tiles per b = ceil(1855/32)
#define NTILE (TPB * B_)   // 14848
#define TPBLK 8            // tiles per block
#define NBLK  (NTILE / TPBLK)   // 1856, % 8 == 0
#define CPX2  (NBLK / 8)        // 232

typedef __bf16 bf16x8 __attribute__((ext_vector_type(8)));
typedef float  f32x4  __attribute__((ext_vector_type(4)));

typedef __attribute__((address_space(3))) unsigned int       lds_u32;
typedef const __attribute__((address_space(1))) unsigned int glb_u32;

static __device__ inline unsigned short f2bf(float f) {
    __hip_bfloat16 h = __float2bfloat16(f);
    return *reinterpret_cast<unsigned short*>(&h);
}

// ---------------------------------------------------------------------------
// Kernel 1: pack weights into MFMA A-fragment order (bf16) + 1/total_valid
// Also zeroes the 128-B zbuf (replaces a hipMemsetAsync whose fill dispatch
// cost ~71 us/replay).
// ---------------------------------------------------------------------------
__global__ void prep_weights(const float* __restrict__ wc,
                             const float* __restrict__ wn,
                             const int*   __restrict__ nb,
                             unsigned short* __restrict__ W2,
                             float* __restrict__ inv_tv,
                             unsigned short* __restrict__ zbuf) {
    int e = blockIdx.x * 256 + threadIdx.x;     // 0 .. 28671
    int j = e & 7;
    int l = (e >> 3) & 63;
    int t = (e >> 9) & 3;
    int s = e >> 11;
    int o = t * 16 + (l & 15);
    int k = s * 32 + (l >> 4) * 8 + j;
    int slot = k >> 6;
    int c = k & 63;
    float v = (slot == 0) ? wc[o * 64 + c]
                          : wn[(o * 64 + c) * 6 + (slot - 1)];
    W2[e] = f2bf(v);
    if (blockIdx.x == 0 && threadIdx.x < 64) zbuf[threadIdx.x] = 0;
    if (e == 0) {
        int cnt = 1;
        #pragma unroll
        for (int q = 0; q < 6; ++q) cnt += (nb[q] >= 0) ? 1 : 0;
        *inv_tv = 1.0f / (float)cnt;
    }
}

// ---------------------------------------------------------------------------
// Kernel 2: transpose + convert  x (B, C, H) fp32  ->  xT (B, H, C) bf16
// ---------------------------------------------------------------------------
__global__ void transpose_bf16(const float* __restrict__ x,
                               unsigned short* __restrict__ xT) {
    __shared__ __align__(16) unsigned short tile[64][72];  // +8 pad
    int b  = blockIdx.y;
    int h0 = blockIdx.x * HT;
    int t  = threadIdx.x;
    int ho = t & 63;
    int cq = t >> 6;                       // 0..3
    const float* xb = x + (size_t)b * CIN * H_;
    int h = h0 + ho;
    #pragma unroll
    for (int i = 0; i < 16; ++i) {
        int c = i * 4 + cq;
        float v = (h < H_) ? xb[(size_t)c * H_ + h] : 0.f;
        tile[ho][c] = f2bf(v);
    }
    __syncthreads();
    #pragma unroll
    for (int rep = 0; rep < 2; ++rep) {
        int task = rep * 256 + t;          // 0..511  = 64 rows * 8 chunks
        int hh = task >> 3;
        int j  = task & 7;
        int hw = h0 + hh;
        if (hw < H_) {
            *reinterpret_cast<uint4*>(&xT[((size_t)b * H_ + hw) * 64 + j * 8]) =
                *reinterpret_cast<const uint4*>(&tile[hh][j * 8]);
        }
    }
}

// ---------------------------------------------------------------------------
// Kernel 3: persistent 8-tile pipeline. 512 threads = 8 waves.
// Staging: wave w (w<7) owns slot w of the NEXT tile via 4 global_load_lds
// (16B, XOR-swizzled source). Counted vmcnt keeps staging in flight across
// the barrier; compute of tile i overlaps staging of tile i+1.
// Compute: wave w -> o-tile og=w&3, h-subtile hh=w>>2; 14 MFMA per tile.
// ---------------------------------------------------------------------------
__global__ __launch_bounds__(512, 4) void conv_main(
        const unsigned short* __restrict__ xT,
        const unsigned short* __restrict__ W2,
        const int*   __restrict__ nb,
        const float* __restrict__ bias,
        const float* __restrict__ inv_tv,
        const unsigned short* __restrict__ zbuf,
        float* __restrict__ out) {
    __shared__ __align__(16) unsigned short feat[2][7][HT2][64]; // 57,344 B

    int bid = blockIdx.x;
    int swz   = (bid & 7) * CPX2 + (bid >> 3);   // bijective XCD swizzle
    int gbase = swz * TPBLK;

    int t = threadIdx.x;
    int w = t >> 6;          // wave 0..7
    int l = t & 63;

    // staging lane constants
    int lrow = l >> 3;                  // h row within an 8-row chunk
    int jsrc = (l & 7) ^ lrow;          // source 16B unit (inverse of read swz)
    int q    = w - 1;                   // neighbor index for waves 1..6

    // compute lane constants
    int og = w & 3, hh = w >> 2;
    int lr = l & 15, lg = l >> 4;
    int hrow = hh * 16 + lr;            // 0..31

    // hoist W fragments + epilogue constants
    const bf16x8* __restrict__ Wf = reinterpret_cast<const bf16x8*>(W2);
    bf16x8 wr[NSTEP];
    #pragma unroll
    for (int s = 0; s < NSTEP; ++s) wr[s] = Wf[(s * 4 + og) * 64 + l];
    float inv = *inv_tv;
    float bv[4];
    #pragma unroll
    for (int r = 0; r < 4; ++r) bv[r] = bias[og * 16 + lg * 4 + r];

    int nbv[4];       // neighbor rows for the tile being staged next
    int bn, h0n;      // b / h0 of that tile

    // ---- prologue: stage tile 0, prefetch nbv for tile 1 -----------------
    if (w < 7) {
        int b0  = gbase / TPB;
        int h00 = (gbase - b0 * TPB) * HT2;
        #pragma unroll
        for (int c = 0; c < 4; ++c) {
            int h = h00 + c * 8 + lrow;
            nbv[c] = (h < H_) ? ((w == 0) ? h : nb[h * 6 + q]) : -1;
        }
        const unsigned short* xb = xT + (size_t)b0 * H_ * 64;
        #pragma unroll
        for (int c = 0; c < 4; ++c) {
            int n = nbv[c];
            const unsigned short* src = (n >= 0)
                ? (xb + (size_t)n * 64 + jsrc * 8) : (zbuf + jsrc * 8);
            __builtin_amdgcn_global_load_lds((glb_u32*)src,
                (lds_u32*)&feat[0][w][c * 8][0], 16, 0, 0);
        }
        int g1 = gbase + 1;
        bn  = g1 / TPB;
        h0n = (g1 - bn * TPB) * HT2;
        #pragma unroll
        for (int c = 0; c < 4; ++c) {
            int h = h0n + c * 8 + lrow;
            nbv[c] = (h < H_) ? ((w == 0) ? h : nb[h * 6 + q]) : -1;
        }
    }

    // ---- main loop over 8 tiles -----------------------------------------
    #pragma unroll 2
    for (int i = 0; i < TPBLK; ++i) {
        // A: issue staging for tile i+1 into buf[(i+1)&1]
        if (i < TPBLK - 1 && w < 7) {
            const unsigned short* xb = xT + (size_t)bn * H_ * 64;
            #pragma unroll
            for (int c = 0; c < 4; ++c) {
                int n = nbv[c];
                const unsigned short* src = (n >= 0)
                    ? (xb + (size_t)n * 64 + jsrc * 8) : (zbuf + jsrc * 8);
                __builtin_amdgcn_global_load_lds((glb_u32*)src,
                    (lds_u32*)&feat[(i + 1) & 1][w][c * 8][0], 16, 0, 0);
            }
        }
        // B: prefetch nbv for tile i+2
        if (i < TPBLK - 2 && w < 7) {
            int g2 = gbase + i + 2;
            bn  = g2 / TPB;
            h0n = (g2 - bn * TPB) * HT2;
            #pragma unroll
            for (int c = 0; c < 4; ++c) {
                int h = h0n + c * 8 + lrow;
                nbv[c] = (h < H_) ? ((w == 0) ? h : nb[h * 6 + q]) : -1;
            }
        }
        // C: counted wait — tile i's staging (issued last iter) is complete.
        // Ops newer than it: 4 g_lds + 4 nb for loader waves (8); wave 0 has
        // no nb loads (4); last iteration has no new staging (4).
        if (w == 0 || i == TPBLK - 1)
            asm volatile("s_waitcnt vmcnt(4)" ::: "memory");
        else
            asm volatile("s_waitcnt vmcnt(8)" ::: "memory");
        __builtin_amdgcn_s_barrier();
        __builtin_amdgcn_sched_barrier(0);

        // E: compute tile i from buf[i&1]
        int cb = i & 1;
        f32x4 acc = (f32x4){0.f, 0.f, 0.f, 0.f};
        #pragma unroll
        for (int s = 0; s < NSTEP; ++s) {
            int c16 = (((s & 1) * 4 + lg)) ^ (hrow & 7);
            bf16x8 bfrag = *reinterpret_cast<const bf16x8*>(
                    &feat[cb][s >> 1][hrow][c16 * 8]);
            acc = __builtin_amdgcn_mfma_f32_16x16x32_bf16(wr[s], bfrag, acc, 0, 0, 0);
        }

        // F: epilogue for tile i
        int g    = gbase + i;
        int curb = g / TPB;
        int curh = (g - curb * TPB) * HT2 + hrow;
        if (curh < H_) {
            float* ob = out + (size_t)curb * COUT * H_ + curh;
            #pragma unroll
            for (int r = 0; r < 4; ++r)
                ob[(size_t)(og * 16 + lg * 4 + r) * H_] = acc[r] * inv + bv[r];
        }

        // G: all reads of buf[i&1] done before next iter overwrites it
        __builtin_amdgcn_s_barrier();
    }
}

// ---------------------------------------------------------------------------
extern "C" void kernel_launch(void* const* d_in, const int* in_sizes, int n_in,
                              void* d_out, int out_size, void* d_ws, size_t ws_size,
                              hipStream_t stream) {
    const float* x    = (const float*)d_in[0];
    const int*   nb   = (const int*)  d_in[1];
    const float* wc   = (const float*)d_in[2];
    const float* wn   = (const float*)d_in[3];
    const float* bias = (const float*)d_in[4];
    float* out = (float*)d_out;

    char* ws = (char*)d_ws;
    unsigned short* W2     = (unsigned short*)ws;            // 57,344 B
    float*          inv_tv = (float*)(ws + 57344);           // 4 B
    unsigned short* zbuf   = (unsigned short*)(ws + 57472);  // 128 B zero
    unsigned short* xT     = (unsigned short*)(ws + 57600);  // 60,784,640 B

    prep_weights<<<112, 256, 0, stream>>>(wc, wn, nb, W2, inv_tv, zbuf);

    dim3 tgrid(NHT, B_);
    transpose_bf16<<<tgrid, 256, 0, stream>>>(x, xT);
    conv_main<<<NBLK, 512, 0, stream>>>(xT, W2, nb, bias, inv_tv, zbuf, out);
}